// Round 1
// baseline (1397.586 us; speedup 1.0000x reference)
//
#include <hip/hip_runtime.h>
#include <hip/hip_bf16.h>

#define GNN_N 50000
#define GNN_E 600000

// ---------------- helpers ----------------
__device__ __forceinline__ unsigned enc_f(float f) {
    unsigned u = __float_as_uint(f);
    return (u & 0x80000000u) ? ~u : (u | 0x80000000u);
}
__device__ __forceinline__ float dec_f(unsigned u) {
    return __uint_as_float((u & 0x80000000u) ? (u ^ 0x80000000u) : ~u);
}
__device__ __forceinline__ float leaky02(float x) { return x > 0.f ? x : 0.2f * x; }

// ---------------- degree ----------------
__global__ void gnn_deg_init(float* deg, int n) {
    int i = blockIdx.x * blockDim.x + threadIdx.x;
    if (i < n) deg[i] = 1.0f;  // self-loop weight
}
__global__ void gnn_deg_acc(const int* __restrict__ dst, const float* __restrict__ ew,
                            float* deg, int e) {
    int i = blockIdx.x * blockDim.x + threadIdx.x;
    if (i < e) atomicAdd(&deg[dst[i]], ew[i]);
}
__global__ void gnn_deg_fin(float* deg, int n) {
    int i = blockIdx.x * blockDim.x + threadIdx.x;
    if (i < n) deg[i] = rsqrtf(deg[i]);  // deg >= 1 always
}

// ---------------- fp32 tiled GEMM: C[M,N] = A[M,K] @ B[K,N] ----------------
// BM=BN=64, BK=16, 256 threads, 4x4 micro-tile. N,K multiples of 16/64 per use.
__global__ __launch_bounds__(256) void gnn_sgemm64(const float* __restrict__ A,
                                                   const float* __restrict__ B,
                                                   float* __restrict__ C,
                                                   int M, int N, int K) {
    __shared__ float As[16][64];
    __shared__ float Bs[16][64];
    const int tid = threadIdx.x;
    const int tx = tid & 15;
    const int ty = tid >> 4;
    const int brow = blockIdx.y << 6;
    const int bcol = blockIdx.x << 6;

    const int am = tid >> 2;          // 0..63 row within tile
    const int ak = (tid & 3) << 2;    // 0,4,8,12
    const int bk = tid >> 4;          // 0..15
    const int bn = (tid & 15) << 2;   // 0..60

    const int arow = brow + am;
    const bool avalid = arow < M;
    const float* Aptr = A + (size_t)(avalid ? arow : 0) * K + ak;
    const float* Bptr = B + (size_t)bk * N + bcol + bn;

    float acc[4][4] = {};

    for (int k0 = 0; k0 < K; k0 += 16) {
        float4 av = avalid ? *(const float4*)(Aptr + k0) : make_float4(0.f, 0.f, 0.f, 0.f);
        float4 bv = *(const float4*)(Bptr + (size_t)k0 * N);
        As[ak + 0][am] = av.x;
        As[ak + 1][am] = av.y;
        As[ak + 2][am] = av.z;
        As[ak + 3][am] = av.w;
        *(float4*)&Bs[bk][bn] = bv;
        __syncthreads();
#pragma unroll
        for (int k = 0; k < 16; ++k) {
            float4 a = *(const float4*)&As[k][ty << 2];
            float4 b = *(const float4*)&Bs[k][tx << 2];
            acc[0][0] += a.x * b.x; acc[0][1] += a.x * b.y; acc[0][2] += a.x * b.z; acc[0][3] += a.x * b.w;
            acc[1][0] += a.y * b.x; acc[1][1] += a.y * b.y; acc[1][2] += a.y * b.z; acc[1][3] += a.y * b.w;
            acc[2][0] += a.z * b.x; acc[2][1] += a.z * b.y; acc[2][2] += a.z * b.z; acc[2][3] += a.z * b.w;
            acc[3][0] += a.w * b.x; acc[3][1] += a.w * b.y; acc[3][2] += a.w * b.z; acc[3][3] += a.w * b.w;
        }
        __syncthreads();
    }
#pragma unroll
    for (int i = 0; i < 4; ++i) {
        int row = brow + (ty << 2) + i;
        if (row < M) {
            float4 v = make_float4(acc[i][0], acc[i][1], acc[i][2], acc[i][3]);
            *(float4*)(C + (size_t)row * N + bcol + (tx << 2)) = v;
        }
    }
}

// ---------------- GCN edge aggregation (wave per edge) ----------------
template <int C>
__global__ void gnn_gcn_edge_agg(const int* __restrict__ src, const int* __restrict__ dst,
                                 const float* __restrict__ ew, const float* __restrict__ dinv,
                                 const float* __restrict__ h, float* __restrict__ out, int e) {
    int wid = (blockIdx.x * blockDim.x + threadIdx.x) >> 6;
    int lane = threadIdx.x & 63;
    if (wid >= e) return;
    int s = src[wid], d = dst[wid];
    float coeff = dinv[s] * ew[wid] * dinv[d];
    const float* hs = h + (size_t)s * C;
    float* od = out + (size_t)d * C;
#pragma unroll
    for (int c = lane; c < C; c += 64) atomicAdd(&od[c], coeff * hs[c]);
}

// out = relu(out + dinv^2 * h + b)   (self loop + bias + relu)
template <int C>
__global__ void gnn_gcn_finalize(const float* __restrict__ h, const float* __restrict__ dinv,
                                 const float* __restrict__ b, float* __restrict__ out, int n) {
    long i = (long)blockIdx.x * blockDim.x + threadIdx.x;
    if (i >= (long)n * C) return;
    int node = (int)(i / C);
    int c = (int)(i & (C - 1));
    float di = dinv[node];
    float v = out[i] + di * di * h[i] + b[c];
    out[i] = v > 0.f ? v : 0.f;
}

// ---------------- GAT ----------------
// a_s[i][h] = dot(h2[i][h*64: h*64+64], att_src[h]); same for a_d. one wave per node.
__global__ void gnn_gat_attn(const float* __restrict__ h2, const float* __restrict__ att_src,
                             const float* __restrict__ att_dst, float* __restrict__ a_s,
                             float* __restrict__ a_d, int n) {
    int wid = (blockIdx.x * blockDim.x + threadIdx.x) >> 6;
    int lane = threadIdx.x & 63;
    if (wid >= n) return;
    const float* hr = h2 + (size_t)wid * 512;
#pragma unroll
    for (int h = 0; h < 8; ++h) {
        float v = hr[h * 64 + lane];
        float ps = v * att_src[h * 64 + lane];
        float pd = v * att_dst[h * 64 + lane];
#pragma unroll
        for (int o = 32; o; o >>= 1) {
            ps += __shfl_xor(ps, o);
            pd += __shfl_xor(pd, o);
        }
        if (lane == 0) {
            a_s[wid * 8 + h] = ps;
            a_d[wid * 8 + h] = pd;
        }
    }
}

// segment max of leaky(a_s[src]+a_d[dst]) per (dst, head); encoded-uint atomicMax.
__global__ void gnn_gat_edge_max(const int* __restrict__ src, const int* __restrict__ dst,
                                 const float* __restrict__ a_s, const float* __restrict__ a_d,
                                 unsigned* __restrict__ menc, int e, int n) {
    int i = blockIdx.x * blockDim.x + threadIdx.x;
    if (i >= e + n) return;
    int s, d;
    if (i < e) { s = src[i]; d = dst[i]; } else { s = d = i - e; }
    const float4* s4 = (const float4*)(a_s + (size_t)s * 8);
    const float4* d4 = (const float4*)(a_d + (size_t)d * 8);
    float4 s0 = s4[0], s1 = s4[1], d0 = d4[0], d1 = d4[1];
    float ev[8] = {s0.x + d0.x, s0.y + d0.y, s0.z + d0.z, s0.w + d0.w,
                   s1.x + d1.x, s1.y + d1.y, s1.z + d1.z, s1.w + d1.w};
#pragma unroll
    for (int h = 0; h < 8; ++h) atomicMax(&menc[(size_t)d * 8 + h], enc_f(leaky02(ev[h])));
}

__global__ void gnn_gat_decode(unsigned* m, int n) {
    int i = blockIdx.x * blockDim.x + threadIdx.x;
    if (i < n) m[i] = __float_as_uint(dec_f(m[i]));
}

__global__ void gnn_gat_edge_sum(const int* __restrict__ src, const int* __restrict__ dst,
                                 const float* __restrict__ a_s, const float* __restrict__ a_d,
                                 const float* __restrict__ mval, float* __restrict__ ssum,
                                 int e, int n) {
    int i = blockIdx.x * blockDim.x + threadIdx.x;
    if (i >= e + n) return;
    int s, d;
    if (i < e) { s = src[i]; d = dst[i]; } else { s = d = i - e; }
    const float4* s4 = (const float4*)(a_s + (size_t)s * 8);
    const float4* d4 = (const float4*)(a_d + (size_t)d * 8);
    float4 s0 = s4[0], s1 = s4[1], d0 = d4[0], d1 = d4[1];
    float ev[8] = {s0.x + d0.x, s0.y + d0.y, s0.z + d0.z, s0.w + d0.w,
                   s1.x + d1.x, s1.y + d1.y, s1.z + d1.z, s1.w + d1.w};
#pragma unroll
    for (int h = 0; h < 8; ++h)
        atomicAdd(&ssum[(size_t)d * 8 + h], __expf(leaky02(ev[h]) - mval[(size_t)d * 8 + h]));
}

// wave per edge: lanes 0..7 compute alpha_h, broadcast, each lane owns channel c=lane.
__global__ void gnn_gat_edge_aggregate(const int* __restrict__ src, const int* __restrict__ dst,
                                       const float* __restrict__ a_s, const float* __restrict__ a_d,
                                       const float* __restrict__ mval, const float* __restrict__ ssum,
                                       const float* __restrict__ h2, float* __restrict__ out,
                                       int e, int n) {
    int wid = (blockIdx.x * blockDim.x + threadIdx.x) >> 6;
    int lane = threadIdx.x & 63;
    if (wid >= e + n) return;
    int s, d;
    if (wid < e) { s = src[wid]; d = dst[wid]; } else { s = d = wid - e; }
    float alpha = 0.f;
    if (lane < 8) {
        float ev = leaky02(a_s[(size_t)s * 8 + lane] + a_d[(size_t)d * 8 + lane]);
        alpha = __expf(ev - mval[(size_t)d * 8 + lane]) / (ssum[(size_t)d * 8 + lane] + 1e-16f);
    }
    float al[8];
#pragma unroll
    for (int h = 0; h < 8; ++h) al[h] = __shfl(alpha, h);
    const float* hs = h2 + (size_t)s * 512;
    float v = 0.f;
#pragma unroll
    for (int h = 0; h < 8; ++h) v += al[h] * hs[h * 64 + lane];
    atomicAdd(&out[(size_t)d * 64 + lane], 0.125f * v);
}

__global__ void gnn_bias_relu64(float* __restrict__ v, const float* __restrict__ b, int n) {
    long i = (long)blockIdx.x * blockDim.x + threadIdx.x;
    if (i >= (long)n * 64) return;
    float t = v[i] + b[i & 63];
    v[i] = t > 0.f ? t : 0.f;
}

// out[i] = dot(g3[i], w) + b   (wave per row)
__global__ void gnn_fc(const float* __restrict__ g3, const float* __restrict__ w,
                       const float* __restrict__ b, float* __restrict__ out, int n) {
    int wid = (blockIdx.x * blockDim.x + threadIdx.x) >> 6;
    int lane = threadIdx.x & 63;
    if (wid >= n) return;
    float v = g3[(size_t)wid * 64 + lane] * w[lane];
#pragma unroll
    for (int o = 32; o; o >>= 1) v += __shfl_xor(v, o);
    if (lane == 0) out[wid] = v + b[0];
}

// ---------------- launch ----------------
extern "C" void kernel_launch(void* const* d_in, const int* in_sizes, int n_in,
                              void* d_out, int out_size, void* d_ws, size_t ws_size,
                              hipStream_t stream) {
    const float* x       = (const float*)d_in[0];
    const int*   ei      = (const int*)d_in[1];
    const float* ew      = (const float*)d_in[2];
    const float* gc1_w   = (const float*)d_in[3];
    const float* gc1_b   = (const float*)d_in[4];
    const float* gat_w   = (const float*)d_in[5];
    const float* att_src = (const float*)d_in[6];
    const float* att_dst = (const float*)d_in[7];
    const float* gat_b   = (const float*)d_in[8];
    const float* gc2_w   = (const float*)d_in[9];
    const float* gc2_b   = (const float*)d_in[10];
    const float* fc_w    = (const float*)d_in[11];
    const float* fc_b    = (const float*)d_in[12];
    float* out = (float*)d_out;

    const int N = GNN_N;
    const int E = in_sizes[2];  // 600000
    const int* src = ei;
    const int* dst = ei + E;

    // workspace layout (bytes)
    char* w = (char*)d_ws;
    const size_t SZ_H2  = (size_t)N * 512 * 4;  // 102.4 MB
    const size_t SZ_128 = (size_t)N * 128 * 4;  // 25.6 MB
    const size_t SZ_64  = (size_t)N * 64 * 4;   // 12.8 MB
    float* h2   = (float*)w;                                  // [N,512] GAT features
    float* h1   = (float*)(w + SZ_H2);                        // [N,128] x@W1
    float* g2   = h1;                                         // [N,64]  reuse after h1 dead
    float* h3   = (float*)(w + SZ_H2 + SZ_64);                // [N,64]  g2@W2 (2nd half of h1 region)
    float* g1   = (float*)(w + SZ_H2 + SZ_128);               // [N,128] GCN1 out
    float* g3   = g1;                                         // [N,64]  reuse after g1 dead
    float* dinv = (float*)(w + SZ_H2 + 2 * SZ_128);           // [N]
    float* a_s  = dinv + N;                                   // [N,8]
    float* a_d  = a_s + (size_t)N * 8;                        // [N,8]
    unsigned* menc = (unsigned*)(a_d + (size_t)N * 8);        // [N,8] enc-max / float max
    float* mval = (float*)menc;
    float* ssum = (float*)(menc + (size_t)N * 8);             // [N,8]

    auto cdiv = [](long a, long b) { return (int)((a + b - 1) / b); };

    // degree / norm
    gnn_deg_init<<<cdiv(N, 256), 256, 0, stream>>>(dinv, N);
    gnn_deg_acc<<<cdiv(E, 256), 256, 0, stream>>>(dst, ew, dinv, E);
    gnn_deg_fin<<<cdiv(N, 256), 256, 0, stream>>>(dinv, N);

    // GCN1: h1 = x @ gc1_w ; g1 = relu(agg + self + b)
    {
        dim3 grid(128 / 64, cdiv(N, 64));
        gnn_sgemm64<<<grid, 256, 0, stream>>>(x, gc1_w, h1, N, 128, 256);
    }
    hipMemsetAsync(g1, 0, SZ_128, stream);
    gnn_gcn_edge_agg<128><<<cdiv((long)E * 64, 256), 256, 0, stream>>>(src, dst, ew, dinv, h1, g1, E);
    gnn_gcn_finalize<128><<<cdiv((long)N * 128, 256), 256, 0, stream>>>(h1, dinv, gc1_b, g1, N);

    // GAT: h2 = g1 @ gat_w
    {
        dim3 grid(512 / 64, cdiv(N, 64));
        gnn_sgemm64<<<grid, 256, 0, stream>>>(g1, gat_w, h2, N, 512, 128);
    }
    gnn_gat_attn<<<cdiv((long)N * 64, 256), 256, 0, stream>>>(h2, att_src, att_dst, a_s, a_d, N);
    hipMemsetAsync(menc, 0, (size_t)N * 8 * 4, stream);
    gnn_gat_edge_max<<<cdiv(E + N, 256), 256, 0, stream>>>(src, dst, a_s, a_d, menc, E, N);
    gnn_gat_decode<<<cdiv((long)N * 8, 256), 256, 0, stream>>>(menc, N * 8);
    hipMemsetAsync(ssum, 0, (size_t)N * 8 * 4, stream);
    gnn_gat_edge_sum<<<cdiv(E + N, 256), 256, 0, stream>>>(src, dst, a_s, a_d, mval, ssum, E, N);
    hipMemsetAsync(g2, 0, SZ_64, stream);
    gnn_gat_edge_aggregate<<<cdiv((long)(E + N) * 64, 256), 256, 0, stream>>>(
        src, dst, a_s, a_d, mval, ssum, h2, g2, E, N);
    gnn_bias_relu64<<<cdiv((long)N * 64, 256), 256, 0, stream>>>(g2, gat_b, N);

    // GCN2: h3 = g2 @ gc2_w ; g3 = relu(agg + self + b)
    {
        dim3 grid(64 / 64, cdiv(N, 64));
        gnn_sgemm64<<<grid, 256, 0, stream>>>(g2, gc2_w, h3, N, 64, 64);
    }
    hipMemsetAsync(g3, 0, SZ_64, stream);
    gnn_gcn_edge_agg<64><<<cdiv((long)E * 64, 256), 256, 0, stream>>>(src, dst, ew, dinv, h3, g3, E);
    gnn_gcn_finalize<64><<<cdiv((long)N * 64, 256), 256, 0, stream>>>(h3, dinv, gc2_b, g3, N);

    // FC
    gnn_fc<<<cdiv((long)N * 64, 256), 256, 0, stream>>>(g3, fc_w, fc_b, out, N);
}

// Round 2
// 672.582 us; speedup vs baseline: 2.0779x; 2.0779x over previous
//
#include <hip/hip_runtime.h>
#include <hip/hip_bf16.h>

#define GNN_N 50000
#define GNN_E 600000

__device__ __forceinline__ float leaky02(float x) { return x > 0.f ? x : 0.2f * x; }

// ---------------- degree / CSR build ----------------
__global__ void gnn_deg_init(float* deg, int n) {
    int i = blockIdx.x * blockDim.x + threadIdx.x;
    if (i < n) deg[i] = 1.0f;  // self-loop weight
}
// histogram of dst + weighted degree in one pass
__global__ void gnn_hist(const int* __restrict__ dst, const float* __restrict__ ew,
                         int* __restrict__ cnt, float* __restrict__ deg, int e) {
    int i = blockIdx.x * blockDim.x + threadIdx.x;
    if (i >= e) return;
    int d = dst[i];
    atomicAdd(&cnt[d], 1);
    atomicAdd(&deg[d], ew[i]);
}
__global__ void gnn_deg_fin(float* deg, int n) {
    int i = blockIdx.x * blockDim.x + threadIdx.x;
    if (i < n) deg[i] = rsqrtf(deg[i]);  // deg >= 1 always
}
// exclusive scan, 1024 elems/block (256 thr x 4)
__global__ void gnn_scan1(const int* __restrict__ cnt, int* __restrict__ row_ptr,
                          int* __restrict__ blksum, int n) {
    __shared__ int sh[256];
    int tid = threadIdx.x;
    int base = blockIdx.x * 1024 + tid * 4;
    int v0 = (base + 0 < n) ? cnt[base + 0] : 0;
    int v1 = (base + 1 < n) ? cnt[base + 1] : 0;
    int v2 = (base + 2 < n) ? cnt[base + 2] : 0;
    int v3 = (base + 3 < n) ? cnt[base + 3] : 0;
    int tsum = v0 + v1 + v2 + v3;
    sh[tid] = tsum;
    __syncthreads();
    for (int off = 1; off < 256; off <<= 1) {
        int t = (tid >= off) ? sh[tid - off] : 0;
        __syncthreads();
        sh[tid] += t;
        __syncthreads();
    }
    int excl = sh[tid] - tsum;
    if (base + 0 < n) row_ptr[base + 0] = excl; excl += v0;
    if (base + 1 < n) row_ptr[base + 1] = excl; excl += v1;
    if (base + 2 < n) row_ptr[base + 2] = excl; excl += v2;
    if (base + 3 < n) row_ptr[base + 3] = excl;
    if (tid == 255) blksum[blockIdx.x] = sh[255];
}
__global__ void gnn_scan2(int* blksum, int nblk, int* row_ptr_end, int total) {
    if (threadIdx.x == 0 && blockIdx.x == 0) {
        int run = 0;
        for (int b = 0; b < nblk; ++b) { int t = blksum[b]; blksum[b] = run; run += t; }
        *row_ptr_end = total;
    }
}
__global__ void gnn_scan3(int* row_ptr, const int* __restrict__ blksum, int n) {
    int i = blockIdx.x * blockDim.x + threadIdx.x;
    if (i < n) row_ptr[i] += blksum[i >> 10];
}
// scatter edges into CSR order; precompute GCN coeff per edge
__global__ void gnn_scatter(const int* __restrict__ src, const int* __restrict__ dst,
                            const float* __restrict__ ew, const float* __restrict__ dinv,
                            const int* __restrict__ row_ptr, int* __restrict__ fill,
                            int* __restrict__ esrc, float* __restrict__ ecw, int e) {
    int i = blockIdx.x * blockDim.x + threadIdx.x;
    if (i >= e) return;
    int d = dst[i];
    int s = src[i];
    int pos = row_ptr[d] + atomicAdd(&fill[d], 1);
    esrc[pos] = s;
    ecw[pos] = dinv[s] * ew[i] * dinv[d];
}

// ---------------- fp32 tiled GEMM: C[M,N] = A[M,K] @ B[K,N] ----------------
__global__ __launch_bounds__(256) void gnn_sgemm64(const float* __restrict__ A,
                                                   const float* __restrict__ B,
                                                   float* __restrict__ C,
                                                   int M, int N, int K) {
    __shared__ float As[16][64];
    __shared__ float Bs[16][64];
    const int tid = threadIdx.x;
    const int tx = tid & 15;
    const int ty = tid >> 4;
    const int brow = blockIdx.y << 6;
    const int bcol = blockIdx.x << 6;

    const int am = tid >> 2;
    const int ak = (tid & 3) << 2;
    const int bk = tid >> 4;
    const int bn = (tid & 15) << 2;

    const int arow = brow + am;
    const bool avalid = arow < M;
    const float* Aptr = A + (size_t)(avalid ? arow : 0) * K + ak;
    const float* Bptr = B + (size_t)bk * N + bcol + bn;

    float acc[4][4] = {};

    for (int k0 = 0; k0 < K; k0 += 16) {
        float4 av = avalid ? *(const float4*)(Aptr + k0) : make_float4(0.f, 0.f, 0.f, 0.f);
        float4 bv = *(const float4*)(Bptr + (size_t)k0 * N);
        As[ak + 0][am] = av.x;
        As[ak + 1][am] = av.y;
        As[ak + 2][am] = av.z;
        As[ak + 3][am] = av.w;
        *(float4*)&Bs[bk][bn] = bv;
        __syncthreads();
#pragma unroll
        for (int k = 0; k < 16; ++k) {
            float4 a = *(const float4*)&As[k][ty << 2];
            float4 b = *(const float4*)&Bs[k][tx << 2];
            acc[0][0] += a.x * b.x; acc[0][1] += a.x * b.y; acc[0][2] += a.x * b.z; acc[0][3] += a.x * b.w;
            acc[1][0] += a.y * b.x; acc[1][1] += a.y * b.y; acc[1][2] += a.y * b.z; acc[1][3] += a.y * b.w;
            acc[2][0] += a.z * b.x; acc[2][1] += a.z * b.y; acc[2][2] += a.z * b.z; acc[2][3] += a.z * b.w;
            acc[3][0] += a.w * b.x; acc[3][1] += a.w * b.y; acc[3][2] += a.w * b.z; acc[3][3] += a.w * b.w;
        }
        __syncthreads();
    }
#pragma unroll
    for (int i = 0; i < 4; ++i) {
        int row = brow + (ty << 2) + i;
        if (row < M) {
            float4 v = make_float4(acc[i][0], acc[i][1], acc[i][2], acc[i][3]);
            *(float4*)(C + (size_t)row * N + bcol + (tx << 2)) = v;
        }
    }
}

// ---------------- GCN per-node gather (fused self-loop + bias + relu) ----------------
template <int C>
__global__ __launch_bounds__(256) void gnn_gcn_node(const int* __restrict__ row_ptr,
                                                    const int* __restrict__ esrc,
                                                    const float* __restrict__ ecw,
                                                    const float* __restrict__ dinv,
                                                    const float* __restrict__ h,
                                                    const float* __restrict__ b,
                                                    float* __restrict__ out, int n) {
    int v = blockIdx.x * 4 + (threadIdx.x >> 6);
    int lane = threadIdx.x & 63;
    if (v >= n) return;
    float di = dinv[v];
    float sc = di * di;
    float acc0 = sc * h[(size_t)v * C + lane];
    float acc1 = 0.f;
    if (C == 128) acc1 = sc * h[(size_t)v * C + 64 + lane];
    int beg = row_ptr[v], end = row_ptr[v + 1];
    for (int p = beg; p < end; ++p) {
        int s = esrc[p];
        float cw = ecw[p];
        acc0 += cw * h[(size_t)s * C + lane];
        if (C == 128) acc1 += cw * h[(size_t)s * C + 64 + lane];
    }
    float o0 = acc0 + b[lane];
    out[(size_t)v * C + lane] = o0 > 0.f ? o0 : 0.f;
    if (C == 128) {
        float o1 = acc1 + b[64 + lane];
        out[(size_t)v * C + 64 + lane] = o1 > 0.f ? o1 : 0.f;
    }
}

// ---------------- GAT ----------------
__global__ __launch_bounds__(256) void gnn_gat_attn(const float* __restrict__ h2,
                                                    const float* __restrict__ att_src,
                                                    const float* __restrict__ att_dst,
                                                    float* __restrict__ a_s,
                                                    float* __restrict__ a_d, int n) {
    int wid = (blockIdx.x * blockDim.x + threadIdx.x) >> 6;
    int lane = threadIdx.x & 63;
    if (wid >= n) return;
    const float* hr = h2 + (size_t)wid * 512;
#pragma unroll
    for (int h = 0; h < 8; ++h) {
        float v = hr[h * 64 + lane];
        float ps = v * att_src[h * 64 + lane];
        float pd = v * att_dst[h * 64 + lane];
#pragma unroll
        for (int o = 32; o; o >>= 1) {
            ps += __shfl_xor(ps, o);
            pd += __shfl_xor(pd, o);
        }
        if (lane == 0) {
            a_s[wid * 8 + h] = ps;
            a_d[wid * 8 + h] = pd;
        }
    }
}

// one wave per node: two-pass softmax over incident edges + weighted gather, heads in regs
__global__ __launch_bounds__(256) void gnn_gat_node(const int* __restrict__ row_ptr,
                                                    const int* __restrict__ esrc,
                                                    const float* __restrict__ a_s,
                                                    const float* __restrict__ a_d,
                                                    const float* __restrict__ h2,
                                                    const float* __restrict__ gat_b,
                                                    float* __restrict__ out, int n) {
    int v = blockIdx.x * 4 + (threadIdx.x >> 6);
    int lane = threadIdx.x & 63;
    if (v >= n) return;

    // per-head vectors of this destination node
    const float4* adp = (const float4*)(a_d + (size_t)v * 8);
    const float4* asp = (const float4*)(a_s + (size_t)v * 8);
    float4 ad0 = adp[0], ad1 = adp[1];
    float4 av0 = asp[0], av1 = asp[1];
    float ad[8]  = {ad0.x, ad0.y, ad0.z, ad0.w, ad1.x, ad1.y, ad1.z, ad1.w};
    float asv[8] = {av0.x, av0.y, av0.z, av0.w, av1.x, av1.y, av1.z, av1.w};

    int beg = row_ptr[v], end = row_ptr[v + 1];

    // ---- pass A: per-head max; lane handles head (lane&7), edge slot (lane>>3)
    int hh = lane & 7;
    float adh = ad[hh];
    float mloc = leaky02(asv[hh] + adh);  // self edge
    for (int p = beg + (lane >> 3); p < end; p += 8) {
        int s = esrc[p];
        mloc = fmaxf(mloc, leaky02(a_s[(size_t)s * 8 + hh] + adh));
    }
    mloc = fmaxf(mloc, __shfl_xor(mloc, 8));
    mloc = fmaxf(mloc, __shfl_xor(mloc, 16));
    mloc = fmaxf(mloc, __shfl_xor(mloc, 32));
    float m_[8];
#pragma unroll
    for (int h = 0; h < 8; ++h) m_[h] = __shfl(mloc, h);

    // ---- pass B: exp-sum + per-head weighted feature accumulation
    float vh[8] = {}, sh[8];
    const float* hv = h2 + (size_t)v * 512;
#pragma unroll
    for (int h = 0; h < 8; ++h) {
        float pp = __expf(leaky02(asv[h] + ad[h]) - m_[h]);
        sh[h] = pp + 1e-16f;
        vh[h] = pp * hv[h * 64 + lane];
    }
    for (int p = beg; p < end; ++p) {
        int s = esrc[p];
        const float4* sp = (const float4*)(a_s + (size_t)s * 8);
        float4 s0 = sp[0], s1 = sp[1];
        float as_[8] = {s0.x, s0.y, s0.z, s0.w, s1.x, s1.y, s1.z, s1.w};
        const float* hs = h2 + (size_t)s * 512;
#pragma unroll
        for (int h = 0; h < 8; ++h) {
            float pp = __expf(leaky02(as_[h] + ad[h]) - m_[h]);
            sh[h] += pp;
            vh[h] += pp * hs[h * 64 + lane];
        }
    }
    float acc = 0.f;
#pragma unroll
    for (int h = 0; h < 8; ++h) acc += vh[h] / sh[h];
    float o = 0.125f * acc + gat_b[lane];
    out[(size_t)v * 64 + lane] = o > 0.f ? o : 0.f;
}

// out[i] = dot(g3[i], w) + b   (wave per row)
__global__ void gnn_fc(const float* __restrict__ g3, const float* __restrict__ w,
                       const float* __restrict__ b, float* __restrict__ out, int n) {
    int wid = (blockIdx.x * blockDim.x + threadIdx.x) >> 6;
    int lane = threadIdx.x & 63;
    if (wid >= n) return;
    float v = g3[(size_t)wid * 64 + lane] * w[lane];
#pragma unroll
    for (int o = 32; o; o >>= 1) v += __shfl_xor(v, o);
    if (lane == 0) out[wid] = v + b[0];
}

// ---------------- launch ----------------
extern "C" void kernel_launch(void* const* d_in, const int* in_sizes, int n_in,
                              void* d_out, int out_size, void* d_ws, size_t ws_size,
                              hipStream_t stream) {
    const float* x       = (const float*)d_in[0];
    const int*   ei      = (const int*)d_in[1];
    const float* ew      = (const float*)d_in[2];
    const float* gc1_w   = (const float*)d_in[3];
    const float* gc1_b   = (const float*)d_in[4];
    const float* gat_w   = (const float*)d_in[5];
    const float* att_src = (const float*)d_in[6];
    const float* att_dst = (const float*)d_in[7];
    const float* gat_b   = (const float*)d_in[8];
    const float* gc2_w   = (const float*)d_in[9];
    const float* gc2_b   = (const float*)d_in[10];
    const float* fc_w    = (const float*)d_in[11];
    const float* fc_b    = (const float*)d_in[12];
    float* out = (float*)d_out;

    const int N = GNN_N;
    const int E = in_sizes[2];
    const int* src = ei;
    const int* dst = ei + E;

    // ---- workspace layout (total ~158.8 MB) ----
    char* w = (char*)d_ws;
    const size_t SZ_H2  = (size_t)N * 512 * 4;   // 102.4 MB
    const size_t SZ_128 = (size_t)N * 128 * 4;   // 25.6 MB
    const size_t SZ_64  = (size_t)N * 64 * 4;    // 12.8 MB
    float* h2 = (float*)w;                        // [N,512]; cnt/fill/blksum alias here pre-GEMM2
    char*  regA = w + SZ_H2;                      // 25.6MB: h1 -> later g2 (0..) and g3 (+12.8MB)
    char*  regB = regA + SZ_128;                  // 25.6MB: g1 -> later a_s, a_d, h3
    float* h1 = (float*)regA;
    float* g2 = (float*)regA;
    float* g3 = (float*)(regA + SZ_64);
    float* g1 = (float*)regB;
    float* a_s = (float*)regB;                    // [N,8] after g1 dead
    float* a_d = (float*)(regB + (size_t)N * 8 * 4);
    float* h3  = (float*)(regB + (size_t)N * 16 * 4);  // [N,64]
    char*  tail = regB + SZ_128;
    float* dinv    = (float*)tail;                         // [N]
    int*   row_ptr = (int*)(tail + (size_t)N * 4);         // [N+1] (+pad)
    int*   esrc    = (int*)(tail + (size_t)N * 4 + 200064);// [E]
    float* ecw     = (float*)((char*)esrc + (size_t)E * 4);// [E]
    // aliased into h2 region (dead before GEMM2 writes h2):
    int* cnt    = (int*)w;
    int* fill   = (int*)(w + (size_t)N * 4);
    int* blksum = (int*)(w + (size_t)N * 8);

    auto cdiv = [](long a, long b) { return (int)((a + b - 1) / b); };

    // ---- CSR build + symmetric norm ----
    hipMemsetAsync(cnt, 0, (size_t)N * 4, stream);
    hipMemsetAsync(fill, 0, (size_t)N * 4, stream);
    gnn_deg_init<<<cdiv(N, 256), 256, 0, stream>>>(dinv, N);
    gnn_hist<<<cdiv(E, 256), 256, 0, stream>>>(dst, ew, cnt, dinv, E);
    gnn_deg_fin<<<cdiv(N, 256), 256, 0, stream>>>(dinv, N);
    const int nblk = cdiv(N, 1024);
    gnn_scan1<<<nblk, 256, 0, stream>>>(cnt, row_ptr, blksum, N);
    gnn_scan2<<<1, 64, 0, stream>>>(blksum, nblk, row_ptr + N, E);
    gnn_scan3<<<cdiv(N, 256), 256, 0, stream>>>(row_ptr, blksum, N);
    gnn_scatter<<<cdiv(E, 256), 256, 0, stream>>>(src, dst, ew, dinv, row_ptr, fill, esrc, ecw, E);

    // ---- GCN1 ----
    {
        dim3 grid(128 / 64, cdiv(N, 64));
        gnn_sgemm64<<<grid, 256, 0, stream>>>(x, gc1_w, h1, N, 128, 256);
    }
    gnn_gcn_node<128><<<cdiv(N, 4), 256, 0, stream>>>(row_ptr, esrc, ecw, dinv, h1, gc1_b, g1, N);

    // ---- GAT ----
    // note: g1 lives in regB which a_s/a_d/h3 will overwrite AFTER this GEMM
    {
        dim3 grid(512 / 64, cdiv(N, 64));
        gnn_sgemm64<<<grid, 256, 0, stream>>>(g1, gat_w, h2, N, 512, 128);
    }
    gnn_gat_attn<<<cdiv((long)N * 64, 256), 256, 0, stream>>>(h2, att_src, att_dst, a_s, a_d, N);
    gnn_gat_node<<<cdiv(N, 4), 256, 0, stream>>>(row_ptr, esrc, a_s, a_d, h2, gat_b, g2, N);

    // ---- GCN2 ----
    {
        dim3 grid(64 / 64, cdiv(N, 64));
        gnn_sgemm64<<<grid, 256, 0, stream>>>(g2, gc2_w, h3, N, 64, 64);
    }
    gnn_gcn_node<64><<<cdiv(N, 4), 256, 0, stream>>>(row_ptr, esrc, ecw, dinv, h3, gc2_b, g3, N);

    // ---- FC ----
    gnn_fc<<<cdiv((long)N * 64, 256), 256, 0, stream>>>(g3, fc_w, fc_b, out, N);
}

// Round 3
// 610.802 us; speedup vs baseline: 2.2881x; 1.1011x over previous
//
#include <hip/hip_runtime.h>
#include <hip/hip_bf16.h>

#define GNN_N 50000
#define GNN_E 600000

typedef unsigned int uint;
typedef unsigned short ushort;
using short8 = __attribute__((ext_vector_type(8))) short;

__device__ __forceinline__ float leaky02(float x) { return x > 0.f ? x : 0.2f * x; }
__device__ __forceinline__ ushort f2b(float f) {  // RNE float->bf16
    uint u = __float_as_uint(f);
    return (ushort)((u + 0x7fffu + ((u >> 16) & 1u)) >> 16);
}
__device__ __forceinline__ float b2f(ushort b) { return __uint_as_float(((uint)b) << 16); }

// ---------------- degree / CSR build ----------------
__global__ void gnn_deg_init(float* deg, int n) {
    int i = blockIdx.x * blockDim.x + threadIdx.x;
    if (i < n) deg[i] = 1.0f;  // self-loop weight
}
__global__ void gnn_hist(const int* __restrict__ dst, const float* __restrict__ ew,
                         int* __restrict__ cnt, float* __restrict__ deg, int e) {
    int i = blockIdx.x * blockDim.x + threadIdx.x;
    if (i >= e) return;
    int d = dst[i];
    atomicAdd(&cnt[d], 1);
    atomicAdd(&deg[d], ew[i]);
}
__global__ void gnn_deg_fin(float* deg, int n) {
    int i = blockIdx.x * blockDim.x + threadIdx.x;
    if (i < n) deg[i] = rsqrtf(deg[i]);
}
__global__ void gnn_scan1(const int* __restrict__ cnt, int* __restrict__ row_ptr,
                          int* __restrict__ blksum, int n) {
    __shared__ int sh[256];
    int tid = threadIdx.x;
    int base = blockIdx.x * 1024 + tid * 4;
    int v0 = (base + 0 < n) ? cnt[base + 0] : 0;
    int v1 = (base + 1 < n) ? cnt[base + 1] : 0;
    int v2 = (base + 2 < n) ? cnt[base + 2] : 0;
    int v3 = (base + 3 < n) ? cnt[base + 3] : 0;
    int tsum = v0 + v1 + v2 + v3;
    sh[tid] = tsum;
    __syncthreads();
    for (int off = 1; off < 256; off <<= 1) {
        int t = (tid >= off) ? sh[tid - off] : 0;
        __syncthreads();
        sh[tid] += t;
        __syncthreads();
    }
    int excl = sh[tid] - tsum;
    if (base + 0 < n) row_ptr[base + 0] = excl; excl += v0;
    if (base + 1 < n) row_ptr[base + 1] = excl; excl += v1;
    if (base + 2 < n) row_ptr[base + 2] = excl; excl += v2;
    if (base + 3 < n) row_ptr[base + 3] = excl;
    if (tid == 255) blksum[blockIdx.x] = sh[255];
}
__global__ void gnn_scan2(int* blksum, int nblk, int* row_ptr_end, int total) {
    if (threadIdx.x == 0 && blockIdx.x == 0) {
        int run = 0;
        for (int b = 0; b < nblk; ++b) { int t = blksum[b]; blksum[b] = run; run += t; }
        *row_ptr_end = total;
    }
}
__global__ void gnn_scan3(int* row_ptr, const int* __restrict__ blksum, int n) {
    int i = blockIdx.x * blockDim.x + threadIdx.x;
    if (i < n) row_ptr[i] += blksum[i >> 10];
}
__global__ void gnn_scatter(const int* __restrict__ src, const int* __restrict__ dst,
                            const float* __restrict__ ew, const float* __restrict__ dinv,
                            const int* __restrict__ row_ptr, int* __restrict__ fill,
                            int* __restrict__ esrc, float* __restrict__ ecw, int e) {
    int i = blockIdx.x * blockDim.x + threadIdx.x;
    if (i >= e) return;
    int d = dst[i];
    int s = src[i];
    int pos = row_ptr[d] + atomicAdd(&fill[d], 1);
    esrc[pos] = s;
    ecw[pos] = dinv[s] * ew[i] * dinv[d];
}

// ---------------- fp32 tiled GEMM -> bf16 out: C[M,N] = A@B ----------------
__global__ __launch_bounds__(256) void gnn_sgemm64_b16(const float* __restrict__ A,
                                                       const float* __restrict__ B,
                                                       ushort* __restrict__ C,
                                                       int M, int N, int K) {
    __shared__ float As[16][64];
    __shared__ float Bs[16][64];
    const int tid = threadIdx.x;
    const int tx = tid & 15;
    const int ty = tid >> 4;
    const int brow = blockIdx.y << 6;
    const int bcol = blockIdx.x << 6;

    const int am = tid >> 2;
    const int ak = (tid & 3) << 2;
    const int bk = tid >> 4;
    const int bn = (tid & 15) << 2;

    const int arow = brow + am;
    const bool avalid = arow < M;
    const float* Aptr = A + (size_t)(avalid ? arow : 0) * K + ak;
    const float* Bptr = B + (size_t)bk * N + bcol + bn;

    float acc[4][4] = {};

    for (int k0 = 0; k0 < K; k0 += 16) {
        float4 av = avalid ? *(const float4*)(Aptr + k0) : make_float4(0.f, 0.f, 0.f, 0.f);
        float4 bv = *(const float4*)(Bptr + (size_t)k0 * N);
        As[ak + 0][am] = av.x;
        As[ak + 1][am] = av.y;
        As[ak + 2][am] = av.z;
        As[ak + 3][am] = av.w;
        *(float4*)&Bs[bk][bn] = bv;
        __syncthreads();
#pragma unroll
        for (int k = 0; k < 16; ++k) {
            float4 a = *(const float4*)&As[k][ty << 2];
            float4 b = *(const float4*)&Bs[k][tx << 2];
            acc[0][0] += a.x * b.x; acc[0][1] += a.x * b.y; acc[0][2] += a.x * b.z; acc[0][3] += a.x * b.w;
            acc[1][0] += a.y * b.x; acc[1][1] += a.y * b.y; acc[1][2] += a.y * b.z; acc[1][3] += a.y * b.w;
            acc[2][0] += a.z * b.x; acc[2][1] += a.z * b.y; acc[2][2] += a.z * b.z; acc[2][3] += a.z * b.w;
            acc[3][0] += a.w * b.x; acc[3][1] += a.w * b.y; acc[3][2] += a.w * b.z; acc[3][3] += a.w * b.w;
        }
        __syncthreads();
    }
#pragma unroll
    for (int i = 0; i < 4; ++i) {
        int row = brow + (ty << 2) + i;
        if (row < M) {
            ushort4 v;
            v.x = f2b(acc[i][0]); v.y = f2b(acc[i][1]); v.z = f2b(acc[i][2]); v.w = f2b(acc[i][3]);
            *(ushort4*)(C + (size_t)row * N + bcol + (tx << 2)) = v;
        }
    }
}

// GEMM2 specialization: N=512 (blockIdx.x == head), writes transposed bf16 h2t[N][64][8]
// and computes a_s/a_d in the epilogue (fused gat_attn).
__global__ __launch_bounds__(256) void gnn_sgemm_gat(const float* __restrict__ A,
                                                     const float* __restrict__ B,
                                                     const float* __restrict__ att_src,
                                                     const float* __restrict__ att_dst,
                                                     ushort* __restrict__ h2t,
                                                     float* __restrict__ a_s,
                                                     float* __restrict__ a_d,
                                                     int M, int K) {
    const int N = 512;
    __shared__ float As[16][64];
    __shared__ float Bs[16][64];
    const int tid = threadIdx.x;
    const int tx = tid & 15;
    const int ty = tid >> 4;
    const int brow = blockIdx.y << 6;
    const int hh = blockIdx.x;      // head
    const int bcol = hh << 6;

    const int am = tid >> 2;
    const int ak = (tid & 3) << 2;
    const int bk = tid >> 4;
    const int bn = (tid & 15) << 2;

    const int arow = brow + am;
    const bool avalid = arow < M;
    const float* Aptr = A + (size_t)(avalid ? arow : 0) * K + ak;
    const float* Bptr = B + (size_t)bk * N + bcol + bn;

    float acc[4][4] = {};

    for (int k0 = 0; k0 < K; k0 += 16) {
        float4 av = avalid ? *(const float4*)(Aptr + k0) : make_float4(0.f, 0.f, 0.f, 0.f);
        float4 bv = *(const float4*)(Bptr + (size_t)k0 * N);
        As[ak + 0][am] = av.x;
        As[ak + 1][am] = av.y;
        As[ak + 2][am] = av.z;
        As[ak + 3][am] = av.w;
        *(float4*)&Bs[bk][bn] = bv;
        __syncthreads();
#pragma unroll
        for (int k = 0; k < 16; ++k) {
            float4 a = *(const float4*)&As[k][ty << 2];
            float4 b = *(const float4*)&Bs[k][tx << 2];
            acc[0][0] += a.x * b.x; acc[0][1] += a.x * b.y; acc[0][2] += a.x * b.z; acc[0][3] += a.x * b.w;
            acc[1][0] += a.y * b.x; acc[1][1] += a.y * b.y; acc[1][2] += a.y * b.z; acc[1][3] += a.y * b.w;
            acc[2][0] += a.z * b.x; acc[2][1] += a.z * b.y; acc[2][2] += a.z * b.z; acc[2][3] += a.z * b.w;
            acc[3][0] += a.w * b.x; acc[3][1] += a.w * b.y; acc[3][2] += a.w * b.z; acc[3][3] += a.w * b.w;
        }
        __syncthreads();
    }

    // ---- store transposed bf16: h2t[row][c][hh], c = tx*4+j ----
#pragma unroll
    for (int i = 0; i < 4; ++i) {
        int row = brow + (ty << 2) + i;
        if (row < M) {
            ushort* dstp = h2t + (size_t)row * 512 + (tx << 2) * 8 + hh;
#pragma unroll
            for (int j = 0; j < 4; ++j) dstp[j * 8] = f2b(acc[i][j]);
        }
    }

    // ---- fused attention dots: a_s[row][hh] = sum_c h2[row][hh*64+c]*att_src[hh][c] ----
    float4 avs = *(const float4*)(att_src + hh * 64 + (tx << 2));
    float4 avd = *(const float4*)(att_dst + hh * 64 + (tx << 2));
    float ps[4], pd[4];
#pragma unroll
    for (int i = 0; i < 4; ++i) {
        ps[i] = acc[i][0] * avs.x + acc[i][1] * avs.y + acc[i][2] * avs.z + acc[i][3] * avs.w;
        pd[i] = acc[i][0] * avd.x + acc[i][1] * avd.y + acc[i][2] * avd.z + acc[i][3] * avd.w;
    }
#pragma unroll
    for (int m = 1; m < 16; m <<= 1) {
#pragma unroll
        for (int i = 0; i < 4; ++i) {
            ps[i] += __shfl_xor(ps[i], m);
            pd[i] += __shfl_xor(pd[i], m);
        }
    }
    if (tx == 0) {
#pragma unroll
        for (int i = 0; i < 4; ++i) {
            int row = brow + (ty << 2) + i;
            if (row < M) {
                a_s[(size_t)row * 8 + hh] = ps[i];
                a_d[(size_t)row * 8 + hh] = pd[i];
            }
        }
    }
}

// ---------------- GCN1 per-node gather: bf16 h table, fused bias+relu ----------------
__global__ __launch_bounds__(256) void gnn_gcn_node128(const int* __restrict__ row_ptr,
                                                       const int* __restrict__ esrc,
                                                       const float* __restrict__ ecw,
                                                       const float* __restrict__ dinv,
                                                       const ushort* __restrict__ hb,
                                                       const float* __restrict__ b,
                                                       float* __restrict__ out, int n) {
    int v = blockIdx.x * 4 + (threadIdx.x >> 6);
    int lane = threadIdx.x & 63;
    if (v >= n) return;
    float di = dinv[v];
    float sc = di * di;
    uint us = *(const uint*)(hb + (size_t)v * 128 + 2 * lane);
    float acc0 = sc * __uint_as_float(us << 16);
    float acc1 = sc * __uint_as_float(us & 0xffff0000u);
    int beg = row_ptr[v], end = row_ptr[v + 1];
    for (int p = beg; p < end; ++p) {
        int s = esrc[p];
        float cw = ecw[p];
        uint u = *(const uint*)(hb + (size_t)s * 128 + 2 * lane);
        acc0 += cw * __uint_as_float(u << 16);
        acc1 += cw * __uint_as_float(u & 0xffff0000u);
    }
    float o0 = acc0 + b[2 * lane];
    float o1 = acc1 + b[2 * lane + 1];
    float2 o;
    o.x = o0 > 0.f ? o0 : 0.f;
    o.y = o1 > 0.f ? o1 : 0.f;
    *(float2*)(out + (size_t)v * 128 + 2 * lane) = o;
}

// ---------------- GAT per-node: single-pass softmax + gather (bf16 h2t[N][64][8]) ------
__global__ __launch_bounds__(256) void gnn_gat_node(const int* __restrict__ row_ptr,
                                                    const int* __restrict__ esrc,
                                                    const float* __restrict__ a_s,
                                                    const float* __restrict__ a_d,
                                                    const ushort* __restrict__ h2t,
                                                    const float* __restrict__ gat_b,
                                                    float* __restrict__ out, int n) {
    int v = blockIdx.x * 4 + (threadIdx.x >> 6);
    int lane = threadIdx.x & 63;
    if (v >= n) return;

    const float4* adp = (const float4*)(a_d + (size_t)v * 8);
    const float4* asp = (const float4*)(a_s + (size_t)v * 8);
    float4 ad0 = adp[0], ad1 = adp[1];
    float4 av0 = asp[0], av1 = asp[1];
    float ad[8]  = {ad0.x, ad0.y, ad0.z, ad0.w, ad1.x, ad1.y, ad1.z, ad1.w};
    float asv[8] = {av0.x, av0.y, av0.z, av0.w, av1.x, av1.y, av1.z, av1.w};

    float sh[8], vh[8];
    {   // self edge
        short8 hs = *(const short8*)(h2t + (size_t)v * 512 + lane * 8);
#pragma unroll
        for (int h = 0; h < 8; ++h) {
            float pp = __expf(leaky02(asv[h] + ad[h]));
            sh[h] = pp;
            vh[h] = pp * b2f((ushort)hs[h]);
        }
    }
    int beg = row_ptr[v], end = row_ptr[v + 1];
    for (int p = beg; p < end; ++p) {
        int s = esrc[p];
        const float4* sp = (const float4*)(a_s + (size_t)s * 8);
        float4 s0 = sp[0], s1 = sp[1];
        float as_[8] = {s0.x, s0.y, s0.z, s0.w, s1.x, s1.y, s1.z, s1.w};
        short8 hs = *(const short8*)(h2t + (size_t)s * 512 + lane * 8);
#pragma unroll
        for (int h = 0; h < 8; ++h) {
            float pp = __expf(leaky02(as_[h] + ad[h]));
            sh[h] += pp;
            vh[h] += pp * b2f((ushort)hs[h]);
        }
    }
    float acc = 0.f;
#pragma unroll
    for (int h = 0; h < 8; ++h) acc += vh[h] / (sh[h] + 1e-16f);
    float o = 0.125f * acc + gat_b[lane];
    out[(size_t)v * 64 + lane] = o > 0.f ? o : 0.f;
}

// ---------------- GCN2 per-node gather + fused FC -> d_out ----------------
__global__ __launch_bounds__(256) void gnn_gcn_node64_fc(const int* __restrict__ row_ptr,
                                                         const int* __restrict__ esrc,
                                                         const float* __restrict__ ecw,
                                                         const float* __restrict__ dinv,
                                                         const ushort* __restrict__ hb,
                                                         const float* __restrict__ b,
                                                         const float* __restrict__ fc_w,
                                                         const float* __restrict__ fc_b,
                                                         float* __restrict__ out, int n) {
    int v = blockIdx.x * 4 + (threadIdx.x >> 6);
    int lane = threadIdx.x & 63;
    if (v >= n) return;
    float di = dinv[v];
    float acc = di * di * b2f(hb[(size_t)v * 64 + lane]);
    int beg = row_ptr[v], end = row_ptr[v + 1];
    for (int p = beg; p < end; ++p) {
        int s = esrc[p];
        acc += ecw[p] * b2f(hb[(size_t)s * 64 + lane]);
    }
    float o = acc + b[lane];
    o = o > 0.f ? o : 0.f;
    float val = o * fc_w[lane];
#pragma unroll
    for (int m = 32; m; m >>= 1) val += __shfl_xor(val, m);
    if (lane == 0) out[v] = val + fc_b[0];
}

// ---------------- launch ----------------
extern "C" void kernel_launch(void* const* d_in, const int* in_sizes, int n_in,
                              void* d_out, int out_size, void* d_ws, size_t ws_size,
                              hipStream_t stream) {
    const float* x       = (const float*)d_in[0];
    const int*   ei      = (const int*)d_in[1];
    const float* ew      = (const float*)d_in[2];
    const float* gc1_w   = (const float*)d_in[3];
    const float* gc1_b   = (const float*)d_in[4];
    const float* gat_w   = (const float*)d_in[5];
    const float* att_src = (const float*)d_in[6];
    const float* att_dst = (const float*)d_in[7];
    const float* gat_b   = (const float*)d_in[8];
    const float* gc2_w   = (const float*)d_in[9];
    const float* gc2_b   = (const float*)d_in[10];
    const float* fc_w    = (const float*)d_in[11];
    const float* fc_b    = (const float*)d_in[12];
    float* out = (float*)d_out;

    const int N = GNN_N;
    const int E = in_sizes[2];
    const int* src = ei;
    const int* dst = ei + E;

    // ---- workspace layout (~118 MB, no aliasing) ----
    char* p = (char*)d_ws;
    ushort* h2t = (ushort*)p; p += (size_t)N * 512 * 2;   // 51.2 MB  [N][64][8] bf16
    ushort* h1b = (ushort*)p; p += (size_t)N * 128 * 2;   // 12.8 MB
    float*  g1  = (float*)p;  p += (size_t)N * 128 * 4;   // 25.6 MB
    float*  g2  = (float*)p;  p += (size_t)N * 64 * 4;    // 12.8 MB
    ushort* h3b = (ushort*)p; p += (size_t)N * 64 * 2;    // 6.4 MB
    float*  a_s = (float*)p;  p += (size_t)N * 8 * 4;
    float*  a_d = (float*)p;  p += (size_t)N * 8 * 4;
    float*  dinv = (float*)p; p += (size_t)N * 4;
    int* row_ptr = (int*)p;   p += (size_t)(N + 64) * 4;
    int* esrc = (int*)p;      p += (size_t)E * 4;
    float* ecw = (float*)p;   p += (size_t)E * 4;
    int* cnt = (int*)p;       p += (size_t)N * 4;
    int* fill = (int*)p;      p += (size_t)N * 4;
    int* blksum = (int*)p;    p += 4096;

    auto cdiv = [](long a, long b) { return (int)((a + b - 1) / b); };

    // ---- CSR build + symmetric norm ----
    hipMemsetAsync(cnt, 0, (size_t)N * 4, stream);
    hipMemsetAsync(fill, 0, (size_t)N * 4, stream);
    gnn_deg_init<<<cdiv(N, 256), 256, 0, stream>>>(dinv, N);
    gnn_hist<<<cdiv(E, 256), 256, 0, stream>>>(dst, ew, cnt, dinv, E);
    gnn_deg_fin<<<cdiv(N, 256), 256, 0, stream>>>(dinv, N);
    const int nblk = cdiv(N, 1024);
    gnn_scan1<<<nblk, 256, 0, stream>>>(cnt, row_ptr, blksum, N);
    gnn_scan2<<<1, 64, 0, stream>>>(blksum, nblk, row_ptr + N, E);
    gnn_scan3<<<cdiv(N, 256), 256, 0, stream>>>(row_ptr, blksum, N);
    gnn_scatter<<<cdiv(E, 256), 256, 0, stream>>>(src, dst, ew, dinv, row_ptr, fill, esrc, ecw, E);

    // ---- GCN1: h1b = bf16(x @ gc1_w); g1 = relu(agg + self + b) ----
    {
        dim3 grid(128 / 64, cdiv(N, 64));
        gnn_sgemm64_b16<<<grid, 256, 0, stream>>>(x, gc1_w, h1b, N, 128, 256);
    }
    gnn_gcn_node128<<<cdiv(N, 4), 256, 0, stream>>>(row_ptr, esrc, ecw, dinv, h1b, gc1_b, g1, N);

    // ---- GAT: h2t = bf16(g1 @ gat_w) transposed; a_s/a_d fused in epilogue ----
    {
        dim3 grid(8, cdiv(N, 64));
        gnn_sgemm_gat<<<grid, 256, 0, stream>>>(g1, gat_w, att_src, att_dst, h2t, a_s, a_d, N, 128);
    }
    gnn_gat_node<<<cdiv(N, 4), 256, 0, stream>>>(row_ptr, esrc, a_s, a_d, h2t, gat_b, g2, N);

    // ---- GCN2 + FC ----
    {
        dim3 grid(64 / 64, cdiv(N, 64));
        gnn_sgemm64_b16<<<grid, 256, 0, stream>>>(g2, gc2_w, h3b, N, 64, 64);
    }
    gnn_gcn_node64_fc<<<cdiv(N, 4), 256, 0, stream>>>(row_ptr, esrc, ecw, dinv, h3b, gc2_b,
                                                      fc_w, fc_b, out, N);
}

// Round 4
// 546.515 us; speedup vs baseline: 2.5573x; 1.1176x over previous
//
#include <hip/hip_runtime.h>
#include <hip/hip_bf16.h>

#define GNN_N 50000
#define GNN_E 600000

typedef unsigned int uint;
typedef unsigned short ushort;
using short8 = __attribute__((ext_vector_type(8))) short;

__device__ __forceinline__ float leaky02(float x) { return x > 0.f ? x : 0.2f * x; }
__device__ __forceinline__ ushort f2b(float f) {  // RNE float->bf16
    uint u = __float_as_uint(f);
    return (ushort)((u + 0x7fffu + ((u >> 16) & 1u)) >> 16);
}
__device__ __forceinline__ float b2f(ushort b) { return __uint_as_float(((uint)b) << 16); }

// ---------------- degree / CSR build ----------------
__global__ void gnn_deg_init(float* deg, int n) {
    int i = blockIdx.x * blockDim.x + threadIdx.x;
    if (i < n) deg[i] = 1.0f;  // self-loop weight
}
__global__ void gnn_hist(const int* __restrict__ dst, const float* __restrict__ ew,
                         int* __restrict__ cnt, float* __restrict__ deg, int e) {
    int i = blockIdx.x * blockDim.x + threadIdx.x;
    if (i >= e) return;
    int d = dst[i];
    atomicAdd(&cnt[d], 1);
    atomicAdd(&deg[d], ew[i]);
}
__global__ void gnn_deg_fin(float* deg, int n) {
    int i = blockIdx.x * blockDim.x + threadIdx.x;
    if (i < n) deg[i] = rsqrtf(deg[i]);
}
__global__ void gnn_scan1(const int* __restrict__ cnt, int* __restrict__ row_ptr,
                          int* __restrict__ blksum, int n) {
    __shared__ int sh[256];
    int tid = threadIdx.x;
    int base = blockIdx.x * 1024 + tid * 4;
    int v0 = (base + 0 < n) ? cnt[base + 0] : 0;
    int v1 = (base + 1 < n) ? cnt[base + 1] : 0;
    int v2 = (base + 2 < n) ? cnt[base + 2] : 0;
    int v3 = (base + 3 < n) ? cnt[base + 3] : 0;
    int tsum = v0 + v1 + v2 + v3;
    sh[tid] = tsum;
    __syncthreads();
    for (int off = 1; off < 256; off <<= 1) {
        int t = (tid >= off) ? sh[tid - off] : 0;
        __syncthreads();
        sh[tid] += t;
        __syncthreads();
    }
    int excl = sh[tid] - tsum;
    if (base + 0 < n) row_ptr[base + 0] = excl; excl += v0;
    if (base + 1 < n) row_ptr[base + 1] = excl; excl += v1;
    if (base + 2 < n) row_ptr[base + 2] = excl; excl += v2;
    if (base + 3 < n) row_ptr[base + 3] = excl;
    if (tid == 255) blksum[blockIdx.x] = sh[255];
}
__global__ void gnn_scan2(int* blksum, int nblk, int* row_ptr_end, int total) {
    if (threadIdx.x == 0 && blockIdx.x == 0) {
        int run = 0;
        for (int b = 0; b < nblk; ++b) { int t = blksum[b]; blksum[b] = run; run += t; }
        *row_ptr_end = total;
    }
}
__global__ void gnn_scan3(int* row_ptr, const int* __restrict__ blksum, int n) {
    int i = blockIdx.x * blockDim.x + threadIdx.x;
    if (i < n) row_ptr[i] += blksum[i >> 10];
}
__global__ void gnn_scatter(const int* __restrict__ src, const int* __restrict__ dst,
                            const float* __restrict__ ew, const float* __restrict__ dinv,
                            const int* __restrict__ row_ptr, int* __restrict__ fill,
                            int* __restrict__ esrc, float* __restrict__ ecw, int e) {
    int i = blockIdx.x * blockDim.x + threadIdx.x;
    if (i >= e) return;
    int d = dst[i];
    int s = src[i];
    int pos = row_ptr[d] + atomicAdd(&fill[d], 1);
    esrc[pos] = s;
    ecw[pos] = dinv[s] * ew[i] * dinv[d];
}

// ---------------- fp32 tiled GEMM -> bf16 out: C[M,N] = A@B ----------------
__global__ __launch_bounds__(256) void gnn_sgemm64_b16(const float* __restrict__ A,
                                                       const float* __restrict__ B,
                                                       ushort* __restrict__ C,
                                                       int M, int N, int K) {
    __shared__ float As[16][68];
    __shared__ float Bs[16][68];
    const int tid = threadIdx.x;
    const int tx = tid & 15;
    const int ty = tid >> 4;
    const int brow = blockIdx.y << 6;
    const int bcol = blockIdx.x << 6;

    const int am = tid >> 2;
    const int ak = (tid & 3) << 2;
    const int bk = tid >> 4;
    const int bn = (tid & 15) << 2;

    const int arow = brow + am;
    const bool avalid = arow < M;
    const float* Aptr = A + (size_t)(avalid ? arow : 0) * K + ak;
    const float* Bptr = B + (size_t)bk * N + bcol + bn;

    float acc[4][4] = {};

    for (int k0 = 0; k0 < K; k0 += 16) {
        float4 av = avalid ? *(const float4*)(Aptr + k0) : make_float4(0.f, 0.f, 0.f, 0.f);
        float4 bv = *(const float4*)(Bptr + (size_t)k0 * N);
        As[ak + 0][am] = av.x;
        As[ak + 1][am] = av.y;
        As[ak + 2][am] = av.z;
        As[ak + 3][am] = av.w;
        *(float4*)&Bs[bk][bn] = bv;
        __syncthreads();
#pragma unroll
        for (int k = 0; k < 16; ++k) {
            float4 a = *(const float4*)&As[k][ty << 2];
            float4 b = *(const float4*)&Bs[k][tx << 2];
            acc[0][0] += a.x * b.x; acc[0][1] += a.x * b.y; acc[0][2] += a.x * b.z; acc[0][3] += a.x * b.w;
            acc[1][0] += a.y * b.x; acc[1][1] += a.y * b.y; acc[1][2] += a.y * b.z; acc[1][3] += a.y * b.w;
            acc[2][0] += a.z * b.x; acc[2][1] += a.z * b.y; acc[2][2] += a.z * b.z; acc[2][3] += a.z * b.w;
            acc[3][0] += a.w * b.x; acc[3][1] += a.w * b.y; acc[3][2] += a.w * b.z; acc[3][3] += a.w * b.w;
        }
        __syncthreads();
    }
#pragma unroll
    for (int i = 0; i < 4; ++i) {
        int row = brow + (ty << 2) + i;
        if (row < M) {
            ushort4 v;
            v.x = f2b(acc[i][0]); v.y = f2b(acc[i][1]); v.z = f2b(acc[i][2]); v.w = f2b(acc[i][3]);
            *(ushort4*)(C + (size_t)row * N + bcol + (tx << 2)) = v;
        }
    }
}

// GEMM2 specialization: N=512 (blockIdx.x == head), natural-layout bf16 h2[N][512],
// a_s/a_d computed in the epilogue (fused gat_attn).
__global__ __launch_bounds__(256) void gnn_sgemm_gat(const float* __restrict__ A,
                                                     const float* __restrict__ B,
                                                     const float* __restrict__ att_src,
                                                     const float* __restrict__ att_dst,
                                                     ushort* __restrict__ h2,
                                                     float* __restrict__ a_s,
                                                     float* __restrict__ a_d,
                                                     int M, int K) {
    const int N = 512;
    __shared__ float As[16][68];
    __shared__ float Bs[16][68];
    const int tid = threadIdx.x;
    const int tx = tid & 15;
    const int ty = tid >> 4;
    const int brow = blockIdx.y << 6;
    const int hh = blockIdx.x;      // head
    const int bcol = hh << 6;

    const int am = tid >> 2;
    const int ak = (tid & 3) << 2;
    const int bk = tid >> 4;
    const int bn = (tid & 15) << 2;

    const int arow = brow + am;
    const bool avalid = arow < M;
    const float* Aptr = A + (size_t)(avalid ? arow : 0) * K + ak;
    const float* Bptr = B + (size_t)bk * N + bcol + bn;

    float acc[4][4] = {};

    for (int k0 = 0; k0 < K; k0 += 16) {
        float4 av = avalid ? *(const float4*)(Aptr + k0) : make_float4(0.f, 0.f, 0.f, 0.f);
        float4 bv = *(const float4*)(Bptr + (size_t)k0 * N);
        As[ak + 0][am] = av.x;
        As[ak + 1][am] = av.y;
        As[ak + 2][am] = av.z;
        As[ak + 3][am] = av.w;
        *(float4*)&Bs[bk][bn] = bv;
        __syncthreads();
#pragma unroll
        for (int k = 0; k < 16; ++k) {
            float4 a = *(const float4*)&As[k][ty << 2];
            float4 b = *(const float4*)&Bs[k][tx << 2];
            acc[0][0] += a.x * b.x; acc[0][1] += a.x * b.y; acc[0][2] += a.x * b.z; acc[0][3] += a.x * b.w;
            acc[1][0] += a.y * b.x; acc[1][1] += a.y * b.y; acc[1][2] += a.y * b.z; acc[1][3] += a.y * b.w;
            acc[2][0] += a.z * b.x; acc[2][1] += a.z * b.y; acc[2][2] += a.z * b.z; acc[2][3] += a.z * b.w;
            acc[3][0] += a.w * b.x; acc[3][1] += a.w * b.y; acc[3][2] += a.w * b.z; acc[3][3] += a.w * b.w;
        }
        __syncthreads();
    }

    // ---- natural-layout bf16 store: h2[row][hh*64 + tx*4 .. +3] (full lines per block) ----
#pragma unroll
    for (int i = 0; i < 4; ++i) {
        int row = brow + (ty << 2) + i;
        if (row < M) {
            ushort4 v;
            v.x = f2b(acc[i][0]); v.y = f2b(acc[i][1]); v.z = f2b(acc[i][2]); v.w = f2b(acc[i][3]);
            *(ushort4*)(h2 + (size_t)row * 512 + bcol + (tx << 2)) = v;
        }
    }

    // ---- fused attention dots: a_s[row][hh] = sum_c h2[row][hh*64+c]*att_src[hh][c] ----
    float4 avs = *(const float4*)(att_src + hh * 64 + (tx << 2));
    float4 avd = *(const float4*)(att_dst + hh * 64 + (tx << 2));
    float ps[4], pd[4];
#pragma unroll
    for (int i = 0; i < 4; ++i) {
        ps[i] = acc[i][0] * avs.x + acc[i][1] * avs.y + acc[i][2] * avs.z + acc[i][3] * avs.w;
        pd[i] = acc[i][0] * avd.x + acc[i][1] * avd.y + acc[i][2] * avd.z + acc[i][3] * avd.w;
    }
#pragma unroll
    for (int m = 1; m < 16; m <<= 1) {
#pragma unroll
        for (int i = 0; i < 4; ++i) {
            ps[i] += __shfl_xor(ps[i], m);
            pd[i] += __shfl_xor(pd[i], m);
        }
    }
    if (tx == 0) {
#pragma unroll
        for (int i = 0; i < 4; ++i) {
            int row = brow + (ty << 2) + i;
            if (row < M) {
                a_s[(size_t)row * 8 + hh] = ps[i];
                a_d[(size_t)row * 8 + hh] = pd[i];
            }
        }
    }
}

// ---------------- GCN1 per-node gather: bf16 h table, fused bias+relu ----------------
__global__ __launch_bounds__(256) void gnn_gcn_node128(const int* __restrict__ row_ptr,
                                                       const int* __restrict__ esrc,
                                                       const float* __restrict__ ecw,
                                                       const float* __restrict__ dinv,
                                                       const ushort* __restrict__ hb,
                                                       const float* __restrict__ b,
                                                       float* __restrict__ out, int n) {
    int v = blockIdx.x * 4 + (threadIdx.x >> 6);
    int lane = threadIdx.x & 63;
    if (v >= n) return;
    float di = dinv[v];
    float sc = di * di;
    uint us = *(const uint*)(hb + (size_t)v * 128 + 2 * lane);
    float acc0 = sc * __uint_as_float(us << 16);
    float acc1 = sc * __uint_as_float(us & 0xffff0000u);
    int beg = row_ptr[v], end = row_ptr[v + 1];
    for (int p = beg; p < end; ++p) {
        int s = esrc[p];
        float cw = ecw[p];
        uint u = *(const uint*)(hb + (size_t)s * 128 + 2 * lane);
        acc0 += cw * __uint_as_float(u << 16);
        acc1 += cw * __uint_as_float(u & 0xffff0000u);
    }
    float o0 = acc0 + b[2 * lane];
    float o1 = acc1 + b[2 * lane + 1];
    float2 o;
    o.x = o0 > 0.f ? o0 : 0.f;
    o.y = o1 > 0.f ? o1 : 0.f;
    *(float2*)(out + (size_t)v * 128 + 2 * lane) = o;
}

// ------- GAT per-node: single-pass softmax + gather (natural bf16 h2[N][512]) -------
__global__ __launch_bounds__(256) void gnn_gat_node(const int* __restrict__ row_ptr,
                                                    const int* __restrict__ esrc,
                                                    const float* __restrict__ a_s,
                                                    const float* __restrict__ a_d,
                                                    const ushort* __restrict__ h2,
                                                    const float* __restrict__ gat_b,
                                                    float* __restrict__ out, int n) {
    int v = blockIdx.x * 4 + (threadIdx.x >> 6);
    int lane = threadIdx.x & 63;
    if (v >= n) return;

    const float4* adp = (const float4*)(a_d + (size_t)v * 8);
    const float4* asp = (const float4*)(a_s + (size_t)v * 8);
    float4 ad0 = adp[0], ad1 = adp[1];
    float4 av0 = asp[0], av1 = asp[1];
    float ad[8]  = {ad0.x, ad0.y, ad0.z, ad0.w, ad1.x, ad1.y, ad1.z, ad1.w};
    float asv[8] = {av0.x, av0.y, av0.z, av0.w, av1.x, av1.y, av1.z, av1.w};

    float sh[8], vh[8];
    {   // self edge
        const ushort* hr = h2 + (size_t)v * 512 + lane;
#pragma unroll
        for (int h = 0; h < 8; ++h) {
            float pp = __expf(leaky02(asv[h] + ad[h]));
            sh[h] = pp;
            vh[h] = pp * b2f(hr[h * 64]);
        }
    }
    int beg = row_ptr[v], end = row_ptr[v + 1];
    for (int p = beg; p < end; ++p) {
        int s = esrc[p];
        const float4* sp = (const float4*)(a_s + (size_t)s * 8);
        float4 s0 = sp[0], s1 = sp[1];
        float as_[8] = {s0.x, s0.y, s0.z, s0.w, s1.x, s1.y, s1.z, s1.w};
        const ushort* hr = h2 + (size_t)s * 512 + lane;
#pragma unroll
        for (int h = 0; h < 8; ++h) {
            float pp = __expf(leaky02(as_[h] + ad[h]));
            sh[h] += pp;
            vh[h] += pp * b2f(hr[h * 64]);
        }
    }
    float acc = 0.f;
#pragma unroll
    for (int h = 0; h < 8; ++h) acc += vh[h] / (sh[h] + 1e-16f);
    float o = 0.125f * acc + gat_b[lane];
    out[(size_t)v * 64 + lane] = o > 0.f ? o : 0.f;
}

// ---------------- GCN2 per-node gather + fused FC -> d_out ----------------
__global__ __launch_bounds__(256) void gnn_gcn_node64_fc(const int* __restrict__ row_ptr,
                                                         const int* __restrict__ esrc,
                                                         const float* __restrict__ ecw,
                                                         const float* __restrict__ dinv,
                                                         const ushort* __restrict__ hb,
                                                         const float* __restrict__ b,
                                                         const float* __restrict__ fc_w,
                                                         const float* __restrict__ fc_b,
                                                         float* __restrict__ out, int n) {
    int v = blockIdx.x * 4 + (threadIdx.x >> 6);
    int lane = threadIdx.x & 63;
    if (v >= n) return;
    float di = dinv[v];
    float acc = di * di * b2f(hb[(size_t)v * 64 + lane]);
    int beg = row_ptr[v], end = row_ptr[v + 1];
    for (int p = beg; p < end; ++p) {
        int s = esrc[p];
        acc += ecw[p] * b2f(hb[(size_t)s * 64 + lane]);
    }
    float o = acc + b[lane];
    o = o > 0.f ? o : 0.f;
    float val = o * fc_w[lane];
#pragma unroll
    for (int m = 32; m; m >>= 1) val += __shfl_xor(val, m);
    if (lane == 0) out[v] = val + fc_b[0];
}

// ---------------- launch ----------------
extern "C" void kernel_launch(void* const* d_in, const int* in_sizes, int n_in,
                              void* d_out, int out_size, void* d_ws, size_t ws_size,
                              hipStream_t stream) {
    const float* x       = (const float*)d_in[0];
    const int*   ei      = (const int*)d_in[1];
    const float* ew      = (const float*)d_in[2];
    const float* gc1_w   = (const float*)d_in[3];
    const float* gc1_b   = (const float*)d_in[4];
    const float* gat_w   = (const float*)d_in[5];
    const float* att_src = (const float*)d_in[6];
    const float* att_dst = (const float*)d_in[7];
    const float* gat_b   = (const float*)d_in[8];
    const float* gc2_w   = (const float*)d_in[9];
    const float* gc2_b   = (const float*)d_in[10];
    const float* fc_w    = (const float*)d_in[11];
    const float* fc_b    = (const float*)d_in[12];
    float* out = (float*)d_out;

    const int N = GNN_N;
    const int E = in_sizes[2];
    const int* src = ei;
    const int* dst = ei + E;

    // ---- workspace layout (~118 MB, no aliasing) ----
    char* p = (char*)d_ws;
    ushort* h2b = (ushort*)p; p += (size_t)N * 512 * 2;   // 51.2 MB  [N][512] bf16 natural
    ushort* h1b = (ushort*)p; p += (size_t)N * 128 * 2;   // 12.8 MB
    float*  g1  = (float*)p;  p += (size_t)N * 128 * 4;   // 25.6 MB
    float*  g2  = (float*)p;  p += (size_t)N * 64 * 4;    // 12.8 MB
    ushort* h3b = (ushort*)p; p += (size_t)N * 64 * 2;    // 6.4 MB
    float*  a_s = (float*)p;  p += (size_t)N * 8 * 4;
    float*  a_d = (float*)p;  p += (size_t)N * 8 * 4;
    float*  dinv = (float*)p; p += (size_t)N * 4;
    int* row_ptr = (int*)p;   p += (size_t)(N + 64) * 4;
    int* esrc = (int*)p;      p += (size_t)E * 4;
    float* ecw = (float*)p;   p += (size_t)E * 4;
    int* cnt = (int*)p;       p += (size_t)N * 4;
    int* fill = (int*)p;      p += (size_t)N * 4;
    int* blksum = (int*)p;    p += 4096;

    auto cdiv = [](long a, long b) { return (int)((a + b - 1) / b); };

    // ---- CSR build + symmetric norm ----
    hipMemsetAsync(cnt, 0, (size_t)N * 4, stream);
    hipMemsetAsync(fill, 0, (size_t)N * 4, stream);
    gnn_deg_init<<<cdiv(N, 256), 256, 0, stream>>>(dinv, N);
    gnn_hist<<<cdiv(E, 256), 256, 0, stream>>>(dst, ew, cnt, dinv, E);
    gnn_deg_fin<<<cdiv(N, 256), 256, 0, stream>>>(dinv, N);
    const int nblk = cdiv(N, 1024);
    gnn_scan1<<<nblk, 256, 0, stream>>>(cnt, row_ptr, blksum, N);
    gnn_scan2<<<1, 64, 0, stream>>>(blksum, nblk, row_ptr + N, E);
    gnn_scan3<<<cdiv(N, 256), 256, 0, stream>>>(row_ptr, blksum, N);
    gnn_scatter<<<cdiv(E, 256), 256, 0, stream>>>(src, dst, ew, dinv, row_ptr, fill, esrc, ecw, E);

    // ---- GCN1: h1b = bf16(x @ gc1_w); g1 = relu(agg + self + b) ----
    {
        dim3 grid(128 / 64, cdiv(N, 64));
        gnn_sgemm64_b16<<<grid, 256, 0, stream>>>(x, gc1_w, h1b, N, 128, 256);
    }
    gnn_gcn_node128<<<cdiv(N, 4), 256, 0, stream>>>(row_ptr, esrc, ecw, dinv, h1b, gc1_b, g1, N);

    // ---- GAT: h2b = bf16(g1 @ gat_w) natural; a_s/a_d fused in epilogue ----
    {
        dim3 grid(8, cdiv(N, 64));
        gnn_sgemm_gat<<<grid, 256, 0, stream>>>(g1, gat_w, att_src, att_dst, h2b, a_s, a_d, N, 128);
    }
    gnn_gat_node<<<cdiv(N, 4), 256, 0, stream>>>(row_ptr, esrc, a_s, a_d, h2b, gat_b, g2, N);

    // ---- GCN2 + FC ----
    {
        dim3 grid(64 / 64, cdiv(N, 64));
        gnn_sgemm64_b16<<<grid, 256, 0, stream>>>(g2, gc2_w, h3b, N, 64, 64);
    }
    gnn_gcn_node64_fc<<<cdiv(N, 4), 256, 0, stream>>>(row_ptr, esrc, ecw, dinv, h3b, gc2_b,
                                                      fc_w, fc_b, out, N);
}

// Round 5
// 472.457 us; speedup vs baseline: 2.9581x; 1.1568x over previous
//
#include <hip/hip_runtime.h>
#include <hip/hip_bf16.h>

#define GNN_N 50000
#define GNN_E 600000

typedef unsigned int uint;
typedef unsigned short ushort;
using short8 = __attribute__((ext_vector_type(8))) short;
using f32x4  = __attribute__((ext_vector_type(4))) float;

__device__ __forceinline__ float leaky02(float x) { return x > 0.f ? x : 0.2f * x; }
__device__ __forceinline__ ushort f2b(float f) {  // RNE float->bf16
    uint u = __float_as_uint(f);
    return (ushort)((u + 0x7fffu + ((u >> 16) & 1u)) >> 16);
}
__device__ __forceinline__ float b2f(ushort b) { return __uint_as_float(((uint)b) << 16); }

// ---------------- degree / CSR build ----------------
__global__ void gnn_deg_init(float* deg, int n) {
    int i = blockIdx.x * blockDim.x + threadIdx.x;
    if (i < n) deg[i] = 1.0f;  // self-loop weight
}
__global__ void gnn_hist(const int* __restrict__ dst, const float* __restrict__ ew,
                         int* __restrict__ cnt, float* __restrict__ deg, int e) {
    int i = blockIdx.x * blockDim.x + threadIdx.x;
    if (i >= e) return;
    int d = dst[i];
    atomicAdd(&cnt[d], 1);
    atomicAdd(&deg[d], ew[i]);
}
__global__ void gnn_deg_fin(float* deg, int n) {
    int i = blockIdx.x * blockDim.x + threadIdx.x;
    if (i < n) deg[i] = rsqrtf(deg[i]);
}
__global__ void gnn_scan1(const int* __restrict__ cnt, int* __restrict__ row_ptr,
                          int* __restrict__ blksum, int n) {
    __shared__ int sh[256];
    int tid = threadIdx.x;
    int base = blockIdx.x * 1024 + tid * 4;
    int v0 = (base + 0 < n) ? cnt[base + 0] : 0;
    int v1 = (base + 1 < n) ? cnt[base + 1] : 0;
    int v2 = (base + 2 < n) ? cnt[base + 2] : 0;
    int v3 = (base + 3 < n) ? cnt[base + 3] : 0;
    int tsum = v0 + v1 + v2 + v3;
    sh[tid] = tsum;
    __syncthreads();
    for (int off = 1; off < 256; off <<= 1) {
        int t = (tid >= off) ? sh[tid - off] : 0;
        __syncthreads();
        sh[tid] += t;
        __syncthreads();
    }
    int excl = sh[tid] - tsum;
    if (base + 0 < n) row_ptr[base + 0] = excl; excl += v0;
    if (base + 1 < n) row_ptr[base + 1] = excl; excl += v1;
    if (base + 2 < n) row_ptr[base + 2] = excl; excl += v2;
    if (base + 3 < n) row_ptr[base + 3] = excl;
    if (tid == 255) blksum[blockIdx.x] = sh[255];
}
__global__ void gnn_scan2(int* blksum, int nblk, int* row_ptr_end, int total) {
    if (threadIdx.x == 0 && blockIdx.x == 0) {
        int run = 0;
        for (int b = 0; b < nblk; ++b) { int t = blksum[b]; blksum[b] = run; run += t; }
        *row_ptr_end = total;
    }
}
__global__ void gnn_scan3(int* row_ptr, const int* __restrict__ blksum, int n) {
    int i = blockIdx.x * blockDim.x + threadIdx.x;
    if (i < n) row_ptr[i] += blksum[i >> 10];
}
__global__ void gnn_scatter(const int* __restrict__ src, const int* __restrict__ dst,
                            const float* __restrict__ ew, const float* __restrict__ dinv,
                            const int* __restrict__ row_ptr, int* __restrict__ fill,
                            int* __restrict__ esrc, float* __restrict__ ecw, int e) {
    int i = blockIdx.x * blockDim.x + threadIdx.x;
    if (i >= e) return;
    int d = dst[i];
    int s = src[i];
    int pos = row_ptr[d] + atomicAdd(&fill[d], 1);
    esrc[pos] = s;
    ecw[pos] = dinv[s] * ew[i] * dinv[d];
}

// ---------------- casts ----------------
__global__ void gnn_cast_bf16(const float* __restrict__ in, ushort* __restrict__ out, int n4) {
    int i = blockIdx.x * 256 + threadIdx.x;
    if (i >= n4) return;
    float4 v = ((const float4*)in)[i];
    ushort4 o;
    o.x = f2b(v.x); o.y = f2b(v.y); o.z = f2b(v.z); o.w = f2b(v.w);
    ((ushort4*)out)[i] = o;
}
// B[K][N] fp32 -> Bt[N][K] bf16
__global__ void gnn_transpose_cast(const float* __restrict__ B, ushort* __restrict__ Bt,
                                   int K, int N) {
    int idx = blockIdx.x * 256 + threadIdx.x;
    if (idx >= K * N) return;
    int k = idx / N, n = idx - k * N;
    Bt[(size_t)n * K + k] = f2b(B[idx]);
}

// ---------------- bf16 MFMA GEMM: C[M][N] = A[M][K] @ Bt[N][K]^T, all bf16 ----------------
// block 256 = 4 waves; block tile 64x64; wave computes 64 rows x 16 cols; K-step 32.
__global__ __launch_bounds__(256) void gnn_mfma_gemm(const ushort* __restrict__ A,
                                                     const ushort* __restrict__ Bt,
                                                     ushort* __restrict__ C,
                                                     int M, int N, int K) {
    __shared__ ushort As[64 * 40];  // [row][k] pad 40 (2-way max bank alias)
    __shared__ ushort Bs[64 * 40];  // [col][k]
    const int tid = threadIdx.x;
    const int wv = tid >> 6, lane = tid & 63;
    const int g = lane >> 4, r = lane & 15;
    const int brow = blockIdx.y << 6, bcol = blockIdx.x << 6;

    const int srow = tid >> 2;          // 0..63
    const int skoff = (tid & 3) << 3;   // 0,8,16,24
    int arow = brow + srow;
    if (arow >= M) arow = M - 1;
    const ushort* Ap = A + (size_t)arow * K + skoff;
    const ushort* Bp = Bt + (size_t)(bcol + srow) * K + skoff;
    ushort* AsW = &As[srow * 40 + skoff];
    ushort* BsW = &Bs[srow * 40 + skoff];

    f32x4 acc[4] = {};

    for (int k0 = 0; k0 < K; k0 += 32) {
        *(short8*)AsW = *(const short8*)(Ap + k0);
        *(short8*)BsW = *(const short8*)(Bp + k0);
        __syncthreads();
        short8 bfrag = *(const short8*)&Bs[(wv * 16 + r) * 40 + g * 8];
#pragma unroll
        for (int mb = 0; mb < 4; ++mb) {
            short8 afrag = *(const short8*)&As[(mb * 16 + r) * 40 + g * 8];
            acc[mb] = __builtin_amdgcn_mfma_f32_16x16x32_bf16(afrag, bfrag, acc[mb], 0, 0, 0);
        }
        __syncthreads();
    }

    const int col = bcol + wv * 16 + r;
#pragma unroll
    for (int mb = 0; mb < 4; ++mb) {
        int rowb = brow + mb * 16 + g * 4;
#pragma unroll
        for (int rr = 0; rr < 4; ++rr) {
            int row = rowb + rr;
            if (row < M) C[(size_t)row * N + col] = f2b(acc[mb][rr]);
        }
    }
}

// ---------------- fp32 tiled GEMM -> bf16 out (GEMM3 only) ----------------
__global__ __launch_bounds__(256) void gnn_sgemm64_b16(const float* __restrict__ A,
                                                       const float* __restrict__ B,
                                                       ushort* __restrict__ C,
                                                       int M, int N, int K) {
    __shared__ float As[16][68];
    __shared__ float Bs[16][68];
    const int tid = threadIdx.x;
    const int tx = tid & 15;
    const int ty = tid >> 4;
    const int brow = blockIdx.y << 6;
    const int bcol = blockIdx.x << 6;

    const int am = tid >> 2;
    const int ak = (tid & 3) << 2;
    const int bk = tid >> 4;
    const int bn = (tid & 15) << 2;

    const int arow = brow + am;
    const bool avalid = arow < M;
    const float* Aptr = A + (size_t)(avalid ? arow : 0) * K + ak;
    const float* Bptr = B + (size_t)bk * N + bcol + bn;

    float acc[4][4] = {};

    for (int k0 = 0; k0 < K; k0 += 16) {
        float4 av = avalid ? *(const float4*)(Aptr + k0) : make_float4(0.f, 0.f, 0.f, 0.f);
        float4 bv = *(const float4*)(Bptr + (size_t)k0 * N);
        As[ak + 0][am] = av.x;
        As[ak + 1][am] = av.y;
        As[ak + 2][am] = av.z;
        As[ak + 3][am] = av.w;
        *(float4*)&Bs[bk][bn] = bv;
        __syncthreads();
#pragma unroll
        for (int k = 0; k < 16; ++k) {
            float4 a = *(const float4*)&As[k][ty << 2];
            float4 b = *(const float4*)&Bs[k][tx << 2];
            acc[0][0] += a.x * b.x; acc[0][1] += a.x * b.y; acc[0][2] += a.x * b.z; acc[0][3] += a.x * b.w;
            acc[1][0] += a.y * b.x; acc[1][1] += a.y * b.y; acc[1][2] += a.y * b.z; acc[1][3] += a.y * b.w;
            acc[2][0] += a.z * b.x; acc[2][1] += a.z * b.y; acc[2][2] += a.z * b.z; acc[2][3] += a.z * b.w;
            acc[3][0] += a.w * b.x; acc[3][1] += a.w * b.y; acc[3][2] += a.w * b.z; acc[3][3] += a.w * b.w;
        }
        __syncthreads();
    }
#pragma unroll
    for (int i = 0; i < 4; ++i) {
        int row = brow + (ty << 2) + i;
        if (row < M) {
            ushort4 v;
            v.x = f2b(acc[i][0]); v.y = f2b(acc[i][1]); v.z = f2b(acc[i][2]); v.w = f2b(acc[i][3]);
            *(ushort4*)(C + (size_t)row * N + bcol + (tx << 2)) = v;
        }
    }
}

// ---------------- GCN1 per-node gather: bf16 in, bf16 out (feeds MFMA GEMM2) ----------------
__global__ __launch_bounds__(256) void gnn_gcn_node128(const int* __restrict__ row_ptr,
                                                       const int* __restrict__ esrc,
                                                       const float* __restrict__ ecw,
                                                       const float* __restrict__ dinv,
                                                       const ushort* __restrict__ hb,
                                                       const float* __restrict__ b,
                                                       ushort* __restrict__ out, int n) {
    int v = blockIdx.x * 4 + (threadIdx.x >> 6);
    int lane = threadIdx.x & 63;
    if (v >= n) return;
    float di = dinv[v];
    float sc = di * di;
    uint us = *(const uint*)(hb + (size_t)v * 128 + 2 * lane);
    float acc0 = sc * __uint_as_float(us << 16);
    float acc1 = sc * __uint_as_float(us & 0xffff0000u);
    int beg = row_ptr[v], end = row_ptr[v + 1];
    for (int p = beg; p < end; ++p) {
        int s = esrc[p];
        float cw = ecw[p];
        uint u = *(const uint*)(hb + (size_t)s * 128 + 2 * lane);
        acc0 += cw * __uint_as_float(u << 16);
        acc1 += cw * __uint_as_float(u & 0xffff0000u);
    }
    float o0 = acc0 + b[2 * lane];
    float o1 = acc1 + b[2 * lane + 1];
    o0 = o0 > 0.f ? o0 : 0.f;
    o1 = o1 > 0.f ? o1 : 0.f;
    uint o = (uint)f2b(o0) | ((uint)f2b(o1) << 16);
    *(uint*)(out + (size_t)v * 128 + 2 * lane) = o;
}

// ---------------- attention dots from bf16 h2 ----------------
__global__ __launch_bounds__(256) void gnn_gat_attn(const ushort* __restrict__ h2,
                                                    const float* __restrict__ att_src,
                                                    const float* __restrict__ att_dst,
                                                    float* __restrict__ a_s,
                                                    float* __restrict__ a_d, int n) {
    int wid = (blockIdx.x * blockDim.x + threadIdx.x) >> 6;
    int lane = threadIdx.x & 63;
    if (wid >= n) return;
    const ushort* hr = h2 + (size_t)wid * 512;
#pragma unroll
    for (int h = 0; h < 8; ++h) {
        float v = b2f(hr[h * 64 + lane]);
        float ps = v * att_src[h * 64 + lane];
        float pd = v * att_dst[h * 64 + lane];
#pragma unroll
        for (int o = 32; o; o >>= 1) {
            ps += __shfl_xor(ps, o);
            pd += __shfl_xor(pd, o);
        }
        if (lane == 0) {
            a_s[wid * 8 + h] = ps;
            a_d[wid * 8 + h] = pd;
        }
    }
}

// ------- GAT per-node: single-pass softmax + gather (natural bf16 h2[N][512]) -------
__global__ __launch_bounds__(256) void gnn_gat_node(const int* __restrict__ row_ptr,
                                                    const int* __restrict__ esrc,
                                                    const float* __restrict__ a_s,
                                                    const float* __restrict__ a_d,
                                                    const ushort* __restrict__ h2,
                                                    const float* __restrict__ gat_b,
                                                    float* __restrict__ out, int n) {
    int v = blockIdx.x * 4 + (threadIdx.x >> 6);
    int lane = threadIdx.x & 63;
    if (v >= n) return;

    const float4* adp = (const float4*)(a_d + (size_t)v * 8);
    const float4* asp = (const float4*)(a_s + (size_t)v * 8);
    float4 ad0 = adp[0], ad1 = adp[1];
    float4 av0 = asp[0], av1 = asp[1];
    float ad[8]  = {ad0.x, ad0.y, ad0.z, ad0.w, ad1.x, ad1.y, ad1.z, ad1.w};
    float asv[8] = {av0.x, av0.y, av0.z, av0.w, av1.x, av1.y, av1.z, av1.w};

    float sh[8], vh[8];
    {   // self edge
        const ushort* hr = h2 + (size_t)v * 512 + lane;
#pragma unroll
        for (int h = 0; h < 8; ++h) {
            float pp = __expf(leaky02(asv[h] + ad[h]));
            sh[h] = pp;
            vh[h] = pp * b2f(hr[h * 64]);
        }
    }
    int beg = row_ptr[v], end = row_ptr[v + 1];
    for (int p = beg; p < end; ++p) {
        int s = esrc[p];
        const float4* sp = (const float4*)(a_s + (size_t)s * 8);
        float4 s0 = sp[0], s1 = sp[1];
        float as_[8] = {s0.x, s0.y, s0.z, s0.w, s1.x, s1.y, s1.z, s1.w};
        const ushort* hr = h2 + (size_t)s * 512 + lane;
#pragma unroll
        for (int h = 0; h < 8; ++h) {
            float pp = __expf(leaky02(as_[h] + ad[h]));
            sh[h] += pp;
            vh[h] += pp * b2f(hr[h * 64]);
        }
    }
    float acc = 0.f;
#pragma unroll
    for (int h = 0; h < 8; ++h) acc += vh[h] / (sh[h] + 1e-16f);
    float o = 0.125f * acc + gat_b[lane];
    out[(size_t)v * 64 + lane] = o > 0.f ? o : 0.f;
}

// ---------------- GCN2 per-node gather + fused FC -> d_out ----------------
__global__ __launch_bounds__(256) void gnn_gcn_node64_fc(const int* __restrict__ row_ptr,
                                                         const int* __restrict__ esrc,
                                                         const float* __restrict__ ecw,
                                                         const float* __restrict__ dinv,
                                                         const ushort* __restrict__ hb,
                                                         const float* __restrict__ b,
                                                         const float* __restrict__ fc_w,
                                                         const float* __restrict__ fc_b,
                                                         float* __restrict__ out, int n) {
    int v = blockIdx.x * 4 + (threadIdx.x >> 6);
    int lane = threadIdx.x & 63;
    if (v >= n) return;
    float di = dinv[v];
    float acc = di * di * b2f(hb[(size_t)v * 64 + lane]);
    int beg = row_ptr[v], end = row_ptr[v + 1];
    for (int p = beg; p < end; ++p) {
        int s = esrc[p];
        acc += ecw[p] * b2f(hb[(size_t)s * 64 + lane]);
    }
    float o = acc + b[lane];
    o = o > 0.f ? o : 0.f;
    float val = o * fc_w[lane];
#pragma unroll
    for (int m = 32; m; m >>= 1) val += __shfl_xor(val, m);
    if (lane == 0) out[v] = val + fc_b[0];
}

// ---------------- launch ----------------
extern "C" void kernel_launch(void* const* d_in, const int* in_sizes, int n_in,
                              void* d_out, int out_size, void* d_ws, size_t ws_size,
                              hipStream_t stream) {
    const float* x       = (const float*)d_in[0];
    const int*   ei      = (const int*)d_in[1];
    const float* ew      = (const float*)d_in[2];
    const float* gc1_w   = (const float*)d_in[3];
    const float* gc1_b   = (const float*)d_in[4];
    const float* gat_w   = (const float*)d_in[5];
    const float* att_src = (const float*)d_in[6];
    const float* att_dst = (const float*)d_in[7];
    const float* gat_b   = (const float*)d_in[8];
    const float* gc2_w   = (const float*)d_in[9];
    const float* gc2_b   = (const float*)d_in[10];
    const float* fc_w    = (const float*)d_in[11];
    const float* fc_b    = (const float*)d_in[12];
    float* out = (float*)d_out;

    const int N = GNN_N;
    const int E = in_sizes[2];
    const int* src = ei;
    const int* dst = ei + E;

    // ---- workspace layout (~131 MB) ----
    char* p = (char*)d_ws;
    ushort* h2b = (ushort*)p; p += (size_t)N * 512 * 2;   // 51.2 MB [N][512] bf16
    ushort* xb  = (ushort*)p; p += (size_t)N * 256 * 2;   // 25.6 MB
    ushort* h1b = (ushort*)p; p += (size_t)N * 128 * 2;   // 12.8 MB
    ushort* g1b = (ushort*)p; p += (size_t)N * 128 * 2;   // 12.8 MB
    float*  g2  = (float*)p;  p += (size_t)N * 64 * 4;    // 12.8 MB
    ushort* h3b = (ushort*)p; p += (size_t)N * 64 * 2;    // 6.4 MB
    ushort* w1t = (ushort*)p; p += (size_t)128 * 256 * 2; // 64 KB
    ushort* w2t = (ushort*)p; p += (size_t)512 * 128 * 2; // 128 KB
    float*  a_s = (float*)p;  p += (size_t)N * 8 * 4;
    float*  a_d = (float*)p;  p += (size_t)N * 8 * 4;
    float*  dinv = (float*)p; p += (size_t)N * 4;
    int* row_ptr = (int*)p;   p += (size_t)(N + 64) * 4;
    int* esrc = (int*)p;      p += (size_t)E * 4;
    float* ecw = (float*)p;   p += (size_t)E * 4;
    int* cnt = (int*)p;       p += (size_t)N * 4;
    int* fill = (int*)p;      p += (size_t)N * 4;
    int* blksum = (int*)p;    p += 4096;

    auto cdiv = [](long a, long b) { return (int)((a + b - 1) / b); };

    // ---- CSR build + symmetric norm ----
    hipMemsetAsync(cnt, 0, (size_t)N * 4, stream);
    hipMemsetAsync(fill, 0, (size_t)N * 4, stream);
    gnn_deg_init<<<cdiv(N, 256), 256, 0, stream>>>(dinv, N);
    gnn_hist<<<cdiv(E, 256), 256, 0, stream>>>(dst, ew, cnt, dinv, E);
    gnn_deg_fin<<<cdiv(N, 256), 256, 0, stream>>>(dinv, N);
    const int nblk = cdiv(N, 1024);
    gnn_scan1<<<nblk, 256, 0, stream>>>(cnt, row_ptr, blksum, N);
    gnn_scan2<<<1, 64, 0, stream>>>(blksum, nblk, row_ptr + N, E);
    gnn_scan3<<<cdiv(N, 256), 256, 0, stream>>>(row_ptr, blksum, N);
    gnn_scatter<<<cdiv(E, 256), 256, 0, stream>>>(src, dst, ew, dinv, row_ptr, fill, esrc, ecw, E);

    // ---- casts for MFMA ----
    gnn_cast_bf16<<<cdiv((long)N * 256 / 4, 256), 256, 0, stream>>>(x, xb, N * 256 / 4);
    gnn_transpose_cast<<<cdiv(256 * 128, 256), 256, 0, stream>>>(gc1_w, w1t, 256, 128);
    gnn_transpose_cast<<<cdiv(128 * 512, 256), 256, 0, stream>>>(gat_w, w2t, 128, 512);

    // ---- GCN1: h1b = bf16(xb @ gc1_w) [MFMA]; g1b = bf16(relu(agg + self + b)) ----
    {
        dim3 grid(128 / 64, cdiv(N, 64));
        gnn_mfma_gemm<<<grid, 256, 0, stream>>>(xb, w1t, h1b, N, 128, 256);
    }
    gnn_gcn_node128<<<cdiv(N, 4), 256, 0, stream>>>(row_ptr, esrc, ecw, dinv, h1b, gc1_b, g1b, N);

    // ---- GAT: h2b = bf16(g1b @ gat_w) [MFMA]; attn dots; per-node softmax-gather ----
    {
        dim3 grid(512 / 64, cdiv(N, 64));
        gnn_mfma_gemm<<<grid, 256, 0, stream>>>(g1b, w2t, h2b, N, 512, 128);
    }
    gnn_gat_attn<<<cdiv((long)N * 64, 256), 256, 0, stream>>>(h2b, att_src, att_dst, a_s, a_d, N);
    gnn_gat_node<<<cdiv(N, 4), 256, 0, stream>>>(row_ptr, esrc, a_s, a_d, h2b, gat_b, g2, N);

    // ---- GCN2 + FC ----
    {
        dim3 grid(64 / 64, cdiv(N, 64));
        gnn_sgemm64_b16<<<grid, 256, 0, stream>>>(g2, gc2_w, h3b, N, 64, 64);
    }
    gnn_gcn_node64_fc<<<cdiv(N, 4), 256, 0, stream>>>(row_ptr, esrc, ecw, dinv, h3b, gc2_b,
                                                      fc_w, fc_b, out, N);
}